// Round 1
// 1048.665 us; speedup vs baseline: 1.0435x; 1.0435x over previous
//
#include <hip/hip_runtime.h>
#include <stdint.h>

#define BB 16
#define NN 32768
#define DD 256
#define OUTD 256
#define TOPK 64
#define NTASK (BB * DD) /* 4096 */
#define THRESH 2.75f
#define CAPMAX 512

typedef unsigned long long u64;
typedef unsigned int u32;

// key = diff_bits(31b) << 15 | (32767 - n). Descending u64 == (diff desc, n asc),
// matching jax.lax.top_k / stable argsort(-diff) tie order.
__device__ __forceinline__ u64 make_key(float diff, int n) {
    union { float f; u32 i; } c; c.f = diff;
    return ((u64)c.i << 15) | (u64)(u32)(32767 - n);
}

// ---- Pass 1: coalesced scan of tem_emb (f32), push survivors (diff >= THRESH) ----
__global__ __launch_bounds__(256) void k_scan(const float4* __restrict__ t4,
                                              const float* __restrict__ h0,
                                              u32* __restrict__ cnt,
                                              u64* __restrict__ surv,
                                              int cap) {
    __shared__ float h0s[DD];
    h0s[threadIdx.x] = h0[threadIdx.x];
    __syncthreads();
    const int total = (BB * NN * DD) / 4; // 2^25 float4 groups
    for (int v = blockIdx.x * blockDim.x + threadIdx.x; v < total; v += gridDim.x * blockDim.x) {
        float4 w = t4[v];
        int d0 = (v & 63) << 2;          // 64 groups per (b,n) row
        int n  = (v >> 6) & (NN - 1);
        int b  = v >> 21;                // NN*DD/4 = 2^21 groups per batch
        float xs[4] = {w.x, w.y, w.z, w.w};
#pragma unroll
        for (int q = 0; q < 4; ++q) {
            float df = fabsf(xs[q] - h0s[d0 + q]);
            if (df >= THRESH) {
                int task = (b << 8) + d0 + q;
                u32 pos = atomicAdd(&cnt[task], 1u);
                if ((int)pos < cap)
                    surv[(size_t)task * cap + pos] = make_key(df, n);
            }
        }
    }
}

// ---- Pass 2: per-task rank-based exact top-64 (keys distinct => rank == slot).
//      Broadcast LDS reads, no barriers in the hot loop, no bank conflicts.
//      Fallback (count under/overflow) folded in: branch is block-uniform. ----
__global__ __launch_bounds__(128) void k_select(const u32* __restrict__ cnt,
                                                const u64* __restrict__ surv,
                                                const float* __restrict__ tem,
                                                const float* __restrict__ h0,
                                                float* __restrict__ feats, int cap) {
    int task = blockIdx.x;
    int c = (int)cnt[task];
    int b = task >> 8, d = task & 255;
    if (c >= TOPK && c <= cap) {
        __shared__ u64 keys[CAPMAX];
        for (int i = threadIdx.x; i < c; i += 128)
            keys[i] = surv[(size_t)task * cap + i];
        __syncthreads();
        for (int i = threadIdx.x; i < c; i += 128) {
            u64 me = keys[i];
            int rank = 0;
#pragma unroll 4
            for (int j = 0; j < c; ++j)
                rank += (keys[j] > me) ? 1 : 0;
            if (rank < TOPK) {
                int n = 32767 - (int)(me & 0x7FFFu);
                feats[task * TOPK + rank] = tem[((size_t)b * NN + n) * DD + d];
            }
        }
    } else {
        // exact serial fallback (correctness net; expected never taken)
        if (threadIdx.x >= 64) return;
        int lane = threadIdx.x;
        float h = h0[d];
        const float* base = tem + (size_t)b * NN * DD + d;
        u64 prev = ~0ull;
        for (int k = 0; k < TOPK; ++k) {
            u64 best = 0ull;
            for (int n = lane; n < NN; n += 64) {
                float df = fabsf(base[(size_t)n * DD] - h);
                u64 key = make_key(df, n);
                if (key < prev && key > best) best = key;
            }
            for (int off = 32; off > 0; off >>= 1) {
                u64 o = __shfl_xor(best, off, 64);
                if (o > best) best = o;
            }
            if (lane == 0) {
                int n = 32767 - (int)(best & 0x7FFFu);
                feats[task * TOPK + k] = base[(size_t)n * DD];
            }
            prev = best;
        }
    }
}

// ---- MLP: one block per output o, 8 waves x 2 batches. Each 64KB weight row is
//      pulled by exactly one CU (L1-shared across its 8 waves); feats stay L2-hot. ----
__global__ __launch_bounds__(512) void k_mlp(const float* __restrict__ mlp_w,
                                             const float* __restrict__ feats,
                                             float* __restrict__ ts_raw) {
    int o = blockIdx.x;
    int wv = threadIdx.x >> 6, lane = threadIdx.x & 63;
    int b0 = wv, b1 = wv + 8;
    const float4* w4 = (const float4*)(mlp_w + (size_t)o * (DD * TOPK));
    const float4* f0 = (const float4*)(feats + b0 * (DD * TOPK));
    const float4* f1 = (const float4*)(feats + b1 * (DD * TOPK));
    float a0 = 0.f, a1 = 0.f;
    for (int j = lane; j < (DD * TOPK) / 4; j += 64) {
        float4 wvv = w4[j];
        float4 x0 = f0[j];
        float4 x1 = f1[j];
        a0 += wvv.x * x0.x + wvv.y * x0.y + wvv.z * x0.z + wvv.w * x0.w;
        a1 += wvv.x * x1.x + wvv.y * x1.y + wvv.z * x1.z + wvv.w * x1.w;
    }
    for (int off = 32; off > 0; off >>= 1) {
        a0 += __shfl_down(a0, off, 64);
        a1 += __shfl_down(a1, off, 64);
    }
    if (lane == 0) {
        ts_raw[b0 * OUTD + o] = a0;
        ts_raw[b1 * OUTD + o] = a1;
    }
}

// ---- GRU cell: one block per batch row, f32 ----
__global__ __launch_bounds__(256) void k_gru(const float* __restrict__ ts_raw,
                                             const float* __restrict__ mlp_b,
                                             const float* __restrict__ h0,
                                             const float* __restrict__ Wr_w,
                                             const float* __restrict__ Wr_b,
                                             const float* __restrict__ Wz_w,
                                             const float* __restrict__ Wz_b,
                                             const float* __restrict__ Wt_w,
                                             const float* __restrict__ Wt_b,
                                             float* __restrict__ h_next) {
    int b = blockIdx.x, o = threadIdx.x;
    __shared__ float comb[2 * OUTD];
    __shared__ float rh[OUTD];
    float ts = ts_raw[b * OUTD + o] + mlp_b[o];
    float h = h0[o];
    comb[o] = ts; comb[OUTD + o] = h;
    __syncthreads();
    const float4* wr = (const float4*)(Wr_w + (size_t)o * 2 * OUTD);
    const float4* wz = (const float4*)(Wz_w + (size_t)o * 2 * OUTD);
    float ar = Wr_b[o], az = Wz_b[o];
    for (int j = 0; j < (2 * OUTD) / 4; ++j) {
        float4 a = wr[j];
        ar += a.x * comb[4 * j] + a.y * comb[4 * j + 1] + a.z * comb[4 * j + 2] + a.w * comb[4 * j + 3];
        float4 c = wz[j];
        az += c.x * comb[4 * j] + c.y * comb[4 * j + 1] + c.z * comb[4 * j + 2] + c.w * comb[4 * j + 3];
    }
    float r = 1.f / (1.f + expf(-ar));
    float z = 1.f / (1.f + expf(-az));
    rh[o] = h * r;
    __syncthreads();
    const float4* wt = (const float4*)(Wt_w + (size_t)o * 2 * OUTD);
    float at = Wt_b[o];
    for (int j = 0; j < OUTD / 4; ++j) {
        float4 a = wt[j];
        at += a.x * comb[4 * j] + a.y * comb[4 * j + 1] + a.z * comb[4 * j + 2] + a.w * comb[4 * j + 3];
    }
    for (int j = 0; j < OUTD / 4; ++j) {
        float4 a = wt[OUTD / 4 + j];
        at += a.x * rh[4 * j] + a.y * rh[4 * j + 1] + a.z * rh[4 * j + 2] + a.w * rh[4 * j + 3];
    }
    float ht = tanhf(at);
    h_next[b * OUTD + o] = z * ht + (1.f - z) * ts;
}

// ---- Broadcast h_next across N, 16B f32 stores ----
__global__ __launch_bounds__(256) void k_bcast(const float* __restrict__ h_next,
                                               float4* __restrict__ out) {
    const int total = (BB * OUTD * NN) / 4; // 2^25
    for (int v = blockIdx.x * blockDim.x + threadIdx.x; v < total; v += gridDim.x * blockDim.x) {
        int row = v >> 13; // NN/4 = 8192 groups per (b,o) row
        float h = h_next[row];
        out[v] = make_float4(h, h, h, h);
    }
}

extern "C" void kernel_launch(void* const* d_in, const int* in_sizes, int n_in,
                              void* d_out, int out_size, void* d_ws, size_t ws_size,
                              hipStream_t stream) {
    const float* tem   = (const float*)d_in[0];
    // d_in[1] = year (unused by reference math)
    const float* h0    = (const float*)d_in[2];
    const float* mlp_w = (const float*)d_in[3];
    const float* mlp_b = (const float*)d_in[4];
    const float* Wr_w  = (const float*)d_in[5];
    const float* Wr_b  = (const float*)d_in[6];
    const float* Wz_w  = (const float*)d_in[7];
    const float* Wz_b  = (const float*)d_in[8];
    const float* Wt_w  = (const float*)d_in[9];
    const float* Wt_b  = (const float*)d_in[10];

    char* ws = (char*)d_ws;
    u32* cnt      = (u32*)ws;                 // 16 KiB
    float* ts_raw = (float*)(ws + 16384);     // 16 KiB
    float* h_next = (float*)(ws + 32768);     // 16 KiB
    float* feats  = (float*)(ws + 49152);     // 1 MiB (4096*64*4)
    const size_t surv_off = 49152 + 1048576;
    u64* surv = (u64*)(ws + surv_off);
    int cap = 0;
    if (ws_size > surv_off) {
        size_t avail = (ws_size - surv_off) / ((size_t)NTASK * 8);
        cap = (int)(avail > CAPMAX ? CAPMAX : avail);
    }

    hipMemsetAsync(cnt, 0, NTASK * sizeof(u32), stream);
    k_scan<<<8192, 256, 0, stream>>>((const float4*)tem, h0, cnt, surv, cap);
    k_select<<<NTASK, 128, 0, stream>>>(cnt, surv, tem, h0, feats, cap);
    k_mlp<<<OUTD, 512, 0, stream>>>(mlp_w, feats, ts_raw);
    k_gru<<<BB, 256, 0, stream>>>(ts_raw, mlp_b, h0, Wr_w, Wr_b, Wz_w, Wz_b, Wt_w, Wt_b, h_next);
    k_bcast<<<8192, 256, 0, stream>>>(h_next, (float4*)d_out);
}